// Round 18
// baseline (158.615 us; speedup 1.0000x reference)
//
#include <hip/hip_runtime.h>
#include <stdint.h>

typedef __attribute__((ext_vector_type(8))) short short8;
typedef __attribute__((ext_vector_type(4))) float f32x4;

#define NEG_FLT_MAX (-3.402823466e38f)

__device__ __forceinline__ unsigned short f2bf(float f) {
  uint32_t u = __float_as_uint(f);
  uint32_t r = (u + 0x7fffu + ((u >> 16) & 1u)) >> 16;
  return (unsigned short)r;
}

__device__ __forceinline__ float bf2f(unsigned short u) {
  return __uint_as_float(((uint32_t)u) << 16);
}

__device__ __forceinline__ void gload16(const void* g, void* l) {
  __builtin_amdgcn_global_load_lds(
      (const __attribute__((address_space(1))) uint32_t*)g,
      (__attribute__((address_space(3))) uint32_t*)l, 16, 0, 0);
}

// ============ PREP: wconv (2560 blk) + V-transpose (1536 blk) + wvec (641 blk) ============
__global__ __launch_bounds__(256) void prep_kernel(
    const float* __restrict__ qw, const float* __restrict__ kw,
    const float* __restrict__ vw, const float* __restrict__ qb,
    const float* __restrict__ kb, float scale,
    unsigned short* __restrict__ qwb, unsigned short* __restrict__ kwb,
    unsigned short* __restrict__ vwt,
    float* __restrict__ bias3, float* __restrict__ w4, float* __restrict__ c4) {
  __shared__ float tile[32][33];
  const int bid = blockIdx.x;
  const int t = threadIdx.x;
  if (bid < 2560) {
    const int idx = bid * 256 + t;
    const int QG = 1024 * 1024 / 4;
    if (idx < QG) {
      float4 v = ((const float4*)qw)[idx];
      ushort4 o;
      o.x = f2bf(v.x); o.y = f2bf(v.y); o.z = f2bf(v.z); o.w = f2bf(v.w);
      ((ushort4*)qwb)[idx] = o;
    } else {
      const int j = idx - QG;
      float4 v = ((const float4*)kw)[j];
      ushort4 o;
      o.x = f2bf(v.x * scale); o.y = f2bf(v.y * scale);
      o.z = f2bf(v.z * scale); o.w = f2bf(v.w * scale);
      ((ushort4*)kwb)[j] = o;
    }
  } else if (bid < 4096) {
    const int j = bid - 2560;
    const int c0 = (j & 31) * 32, r0 = (j >> 5) * 32;
    const int tx = t & 31, ty = t >> 5;
#pragma unroll
    for (int i = ty; i < 32; i += 8)
      tile[i][tx] = vw[(size_t)(r0 + i) * 1024 + (c0 + tx)];
    __syncthreads();
#pragma unroll
    for (int i = ty; i < 32; i += 8)
      vwt[(size_t)(c0 + i) * 1536 + (r0 + tx)] = f2bf(tile[tx][i]);
  } else {
    const int idx = bid - 4096;
    const int wv = t >> 6, l = t & 63;
    float s = 0.f;
    if (idx < 256) {
      const int i = idx * 4 + wv;
      const float* row = qw + (size_t)i * 1024;
#pragma unroll
      for (int s0 = 0; s0 < 1024; s0 += 256) {
        float4 a = *(const float4*)(row + s0 + l * 4);
        float4 b = *(const float4*)(kb + s0 + l * 4);
        s += a.x * b.x + a.y * b.y + a.z * b.z + a.w * b.w;
      }
#pragma unroll
      for (int off = 32; off; off >>= 1) s += __shfl_xor(s, off);
      if (l == 0) bias3[i] = s * scale;
    } else if (idx < 640) {
      const int j = (idx - 256) * 4 + wv;
      const float* row = kw + (size_t)j * 1024;
#pragma unroll
      for (int s0 = 0; s0 < 1024; s0 += 256) {
        float4 a = *(const float4*)(row + s0 + l * 4);
        float4 b = *(const float4*)(qb + s0 + l * 4);
        s += a.x * b.x + a.y * b.y + a.z * b.z + a.w * b.w;
      }
#pragma unroll
      for (int off = 32; off; off >>= 1) s += __shfl_xor(s, off);
      if (l == 0) w4[j] = s * scale;
    } else if (wv == 0) {
#pragma unroll
      for (int s0 = 0; s0 < 1024; s0 += 256) {
        float4 a = *(const float4*)(qb + s0 + l * 4);
        float4 b = *(const float4*)(kb + s0 + l * 4);
        s += a.x * b.x + a.y * b.y + a.z * b.z + a.w * b.w;
      }
#pragma unroll
      for (int off = 32; off; off >>= 1) s += __shfl_xor(s, off);
      if (l == 0) *c4 = s * scale;
    }
  }
}

// ---------------- GEMM core, BK=64 (proven r5 structure; used by mid's W3) ----------
__device__ __forceinline__ void gemm_core64(
    const unsigned short* __restrict__ A, int lda, int rowmaxA, int tm0,
    const unsigned short* __restrict__ Bt, int ldb, int rowmaxB, int tn0,
    int K, unsigned short* As, unsigned short* Bs, f32x4 acc[4][4]) {
  const int tid = threadIdx.x;
  const int w = tid >> 6, l = tid & 63;
  const int wr = w >> 1, wc = w & 1;
  const int srow = (w << 4) + (l >> 2);
  const int scol = (l & 3) << 3;
  int ra0 = tm0 + srow;      if (ra0 > rowmaxA) ra0 = rowmaxA;
  int ra1 = tm0 + srow + 64; if (ra1 > rowmaxA) ra1 = rowmaxA;
  int rb0 = tn0 + srow;      if (rb0 > rowmaxB) rb0 = rowmaxB;
  int rb1 = tn0 + srow + 64; if (rb1 > rowmaxB) rb1 = rowmaxB;
  const unsigned short* pa0 = A + (size_t)ra0 * lda + scol;
  const unsigned short* pa1 = A + (size_t)ra1 * lda + scol;
  const unsigned short* pb0 = Bt + (size_t)rb0 * ldb + scol;
  const unsigned short* pb1 = Bt + (size_t)rb1 * ldb + scol;
  unsigned short* la0 = As + (w << 4) * 32;
  unsigned short* la1 = As + ((w << 4) + 64) * 32;
  unsigned short* lb0 = Bs + (w << 4) * 32;
  unsigned short* lb1 = Bs + ((w << 4) + 64) * 32;
  const int foff = ((l & 15) << 5) + ((l >> 4) << 3);
  const unsigned short* fa = As + (wr << 6) * 32 + foff;
  const unsigned short* fb = Bs + (wc << 6) * 32 + foff;
#pragma unroll
  for (int i = 0; i < 4; i++)
#pragma unroll
    for (int j = 0; j < 4; j++) acc[i][j] = (f32x4)0.0f;
  for (int k0 = 0; k0 < K; k0 += 64) {
    gload16(pa0 + k0, la0);
    gload16(pa1 + k0, la1);
    gload16(pb0 + k0, lb0);
    gload16(pb1 + k0, lb1);
    gload16(pa0 + k0 + 32, la0 + 4096);
    gload16(pa1 + k0 + 32, la1 + 4096);
    gload16(pb0 + k0 + 32, lb0 + 4096);
    gload16(pb1 + k0 + 32, lb1 + 4096);
    __syncthreads();
    {
      short8 a[4], b[4];
#pragma unroll
      for (int i = 0; i < 4; i++) a[i] = *(const short8*)(fa + i * 512);
#pragma unroll
      for (int j = 0; j < 4; j++) b[j] = *(const short8*)(fb + j * 512);
#pragma unroll
      for (int i = 0; i < 4; i++)
#pragma unroll
        for (int j = 0; j < 4; j++)
          acc[i][j] = __builtin_amdgcn_mfma_f32_16x16x32_bf16(a[i], b[j], acc[i][j], 0, 0, 0);
    }
    {
      short8 a[4], b[4];
#pragma unroll
      for (int i = 0; i < 4; i++) a[i] = *(const short8*)(fa + 4096 + i * 512);
#pragma unroll
      for (int j = 0; j < 4; j++) b[j] = *(const short8*)(fb + 4096 + j * 512);
#pragma unroll
      for (int i = 0; i < 4; i++)
#pragma unroll
        for (int j = 0; j < 4; j++)
          acc[i][j] = __builtin_amdgcn_mfma_f32_16x16x32_bf16(a[i], b[j], acc[i][j], 0, 0, 0);
    }
    __syncthreads();
  }
}

// ============ MID: ln_box (+fused qbk) for blocks <3200; W3 GEMM for the rest ============
__global__ __launch_bounds__(256) void mid_kernel(
    const float* __restrict__ box,
    const float* __restrict__ klnw, const float* __restrict__ klnb,
    const float* __restrict__ vlnw, const float* __restrict__ vlnb,
    const unsigned short* __restrict__ qwb, const unsigned short* __restrict__ kwb,
    const float* __restrict__ w4v, const float* __restrict__ c4,
    unsigned short* __restrict__ kn, unsigned short* __restrict__ vn,
    unsigned short* __restrict__ W3, float* __restrict__ qbk) {
  __shared__ float red[8];
  __shared__ float redq[4];
  __shared__ unsigned short As[128 * 64];
  __shared__ unsigned short Bs[128 * 64];
  const int t = threadIdx.x;
  if (blockIdx.x < 3200) {
    const int row = blockIdx.x;
    const float4* xr = (const float4*)(box + (size_t)row * 1536);
    const float4 a = xr[t];
    float4 c = make_float4(0.f, 0.f, 0.f, 0.f);
    if (t < 128) c = xr[256 + t];
    float s = a.x + a.y + a.z + a.w + c.x + c.y + c.z + c.w;
    float ss = a.x * a.x + a.y * a.y + a.z * a.z + a.w * a.w +
               c.x * c.x + c.y * c.y + c.z * c.z + c.w * c.w;
#pragma unroll
    for (int off = 32; off > 0; off >>= 1) {
      s += __shfl_xor(s, off);
      ss += __shfl_xor(ss, off);
    }
    if ((t & 63) == 0) { red[(t >> 6) * 2] = s; red[(t >> 6) * 2 + 1] = ss; }
    __syncthreads();
    if (t == 0) {
      float aa = 0.f, bb = 0.f;
      for (int i = 0; i < 4; i++) { aa += red[i * 2]; bb += red[i * 2 + 1]; }
      red[0] = aa; red[1] = bb;
    }
    __syncthreads();
    s = red[0]; ss = red[1];
    const float m = s * (1.f / 1536.f);
    const float var = ss * (1.f / 1536.f) - m * m;
    const float rstd = rsqrtf(var + 1e-5f);
    float qd;
    {
      const float4 w4 = ((const float4*)klnw)[t];
      const float4 b4 = ((const float4*)klnb)[t];
      const float k0v = (a.x - m) * rstd * w4.x + b4.x;
      const float k1v = (a.y - m) * rstd * w4.y + b4.y;
      const float k2v = (a.z - m) * rstd * w4.z + b4.z;
      const float k3v = (a.w - m) * rstd * w4.w + b4.w;
      ushort4 o;
      o.x = f2bf(k0v); o.y = f2bf(k1v); o.z = f2bf(k2v); o.w = f2bf(k3v);
      ((ushort4*)(kn + (size_t)row * 1536))[t] = o;
      const float4 wq = ((const float4*)w4v)[t];
      qd = k0v * wq.x + k1v * wq.y + k2v * wq.z + k3v * wq.w;
      const float4 w4vv = ((const float4*)vlnw)[t];
      const float4 b4vv = ((const float4*)vlnb)[t];
      o.x = f2bf((a.x - m) * rstd * w4vv.x + b4vv.x);
      o.y = f2bf((a.y - m) * rstd * w4vv.y + b4vv.y);
      o.z = f2bf((a.z - m) * rstd * w4vv.z + b4vv.z);
      o.w = f2bf((a.w - m) * rstd * w4vv.w + b4vv.w);
      ((ushort4*)(vn + (size_t)row * 1536))[t] = o;
    }
    if (t < 128) {
      const int t2 = 256 + t;
      const float4 w4 = ((const float4*)klnw)[t2];
      const float4 b4 = ((const float4*)klnb)[t2];
      const float k0v = (c.x - m) * rstd * w4.x + b4.x;
      const float k1v = (c.y - m) * rstd * w4.y + b4.y;
      const float k2v = (c.z - m) * rstd * w4.z + b4.z;
      const float k3v = (c.w - m) * rstd * w4.w + b4.w;
      ushort4 o;
      o.x = f2bf(k0v); o.y = f2bf(k1v); o.z = f2bf(k2v); o.w = f2bf(k3v);
      ((ushort4*)(kn + (size_t)row * 1536))[t2] = o;
      const float4 wq = ((const float4*)w4v)[t2];
      qd += k0v * wq.x + k1v * wq.y + k2v * wq.z + k3v * wq.w;
      const float4 w4vv = ((const float4*)vlnw)[t2];
      const float4 b4vv = ((const float4*)vlnb)[t2];
      o.x = f2bf((c.x - m) * rstd * w4vv.x + b4vv.x);
      o.y = f2bf((c.y - m) * rstd * w4vv.y + b4vv.y);
      o.z = f2bf((c.z - m) * rstd * w4vv.z + b4vv.z);
      o.w = f2bf((c.w - m) * rstd * w4vv.w + b4vv.w);
      ((ushort4*)(vn + (size_t)row * 1536))[t2] = o;
    }
#pragma unroll
    for (int off = 32; off; off >>= 1) qd += __shfl_xor(qd, off);
    if ((t & 63) == 0) redq[t >> 6] = qd;
    __syncthreads();
    if (t == 0) qbk[row] = redq[0] + redq[1] + redq[2] + redq[3] + c4[0];
  } else {
    const int j = blockIdx.x - 3200;
    const int tm0 = (j & 7) * 128, tn0 = (j >> 3) * 128;
    f32x4 acc[4][4];
    gemm_core64(qwb, 1024, 1023, tm0, kwb, 1024, 1535, tn0, 1024, As, Bs, acc);
    const int w = t >> 6, l = t & 63;
    const int wr = w >> 1, wc = w & 1;
#pragma unroll
    for (int i = 0; i < 4; i++) {
      const int row0 = tm0 + wr * 64 + i * 16 + (l >> 4) * 4;
#pragma unroll
      for (int jj = 0; jj < 4; jj++) {
        const int col = tn0 + wc * 64 + jj * 16 + (l & 15);
#pragma unroll
        for (int r = 0; r < 4; r++)
          W3[(size_t)(row0 + r) * 1536 + col] = f2bf(acc[i][jj][r]);
      }
    }
  }
}

// ========= kq + vT projections: 128x64 tiles, 800 blocks, XCD-swizzled =========
// 4 waves as 2(M)x2(N); per-wave 64x32 output (4x2 frags). LDS 24 KB -> 6 blk/CU cap.
__global__ __launch_bounds__(256) void gemm_kv_kernel(
    const unsigned short* __restrict__ kn, const unsigned short* __restrict__ vn,
    const unsigned short* __restrict__ W3, const unsigned short* __restrict__ vwt,
    const float* __restrict__ bias3, const float* __restrict__ vb,
    unsigned short* __restrict__ kq, unsigned short* __restrict__ vT) {
  __shared__ unsigned short As[128 * 64];  // [2kh][128][32]
  __shared__ unsigned short Bs[64 * 64];   // [2kh][64][32]
  const int id = blockIdx.x;
  const int sw = (id & 7) * 100 + (id >> 3);  // bijective: 800 = 8*100
  const int z = sw / 400;
  const int rem = sw - z * 400;
  const int tm0 = (rem % 25) * 128, tn0 = (rem / 25) * 64;
  const unsigned short* A = z ? vn : kn;
  const unsigned short* Bt = z ? vwt : W3;
  const float* bias = z ? vb : bias3;
  const int t = threadIdx.x;
  const int w = t >> 6, l = t & 63;
  const int wr = w >> 1, wc = w & 1;
  const int lo = l & 15, hi = l >> 4;
  const int srow = t >> 2;             // 0..63
  const int scol = (t & 3) << 3;       // 0/8/16/24
  int ra0 = tm0 + srow;      if (ra0 > 3199) ra0 = 3199;
  int ra1 = tm0 + 64 + srow; if (ra1 > 3199) ra1 = 3199;
  const unsigned short* pa0 = A + (size_t)ra0 * 1536 + scol;
  const unsigned short* pa1 = A + (size_t)ra1 * 1536 + scol;
  const unsigned short* pb0 = Bt + (size_t)(tn0 + srow) * 1536 + scol;
  unsigned short* la0 = As + (w << 9);           // rows 0-63, kh0
  unsigned short* la1 = As + 2048 + (w << 9);    // rows 64-127, kh0
  unsigned short* lb0 = Bs + (w << 9);           // rows 0-63, kh0

  f32x4 acc[4][2];
#pragma unroll
  for (int i = 0; i < 4; i++) { acc[i][0] = (f32x4)0.0f; acc[i][1] = (f32x4)0.0f; }

  for (int k0 = 0; k0 < 1536; k0 += 64) {
    gload16(pa0 + k0, la0);
    gload16(pa1 + k0, la1);
    gload16(pb0 + k0, lb0);
    gload16(pa0 + k0 + 32, la0 + 4096);
    gload16(pa1 + k0 + 32, la1 + 4096);
    gload16(pb0 + k0 + 32, lb0 + 2048);
    __syncthreads();
#pragma unroll
    for (int kh = 0; kh < 2; kh++) {
      short8 a[4], b[2];
#pragma unroll
      for (int i = 0; i < 4; i++)
        a[i] = *(const short8*)(As + kh * 4096 + ((wr << 6) + i * 16 + lo) * 32 + hi * 8);
#pragma unroll
      for (int j = 0; j < 2; j++)
        b[j] = *(const short8*)(Bs + kh * 2048 + ((wc << 5) + j * 16 + lo) * 32 + hi * 8);
#pragma unroll
      for (int i = 0; i < 4; i++)
#pragma unroll
        for (int j = 0; j < 2; j++)
          acc[i][j] = __builtin_amdgcn_mfma_f32_16x16x32_bf16(a[i], b[j], acc[i][j], 0, 0, 0);
    }
    __syncthreads();
  }

#pragma unroll
  for (int i = 0; i < 4; i++) {
    const int row0 = tm0 + (wr << 6) + i * 16 + hi * 4;
#pragma unroll
    for (int j = 0; j < 2; j++) {
      const int col = tn0 + (wc << 5) + j * 16 + lo;
      const float bv = bias[col];
#pragma unroll
      for (int r = 0; r < 4; r++) {
        const int row = row0 + r;
        const float val = acc[i][j][r] + bv;
        if (!z) {
          kq[(size_t)row * 1024 + col] = f2bf(val);
        } else {
          const int bb = row / 100;
          const int ll = row - bb * 100;
          vT[((size_t)bb * 1024 + col) * 128 + ll] = f2bf(val);
        }
      }
    }
  }
}

// ---------------- block reduction helper ----------------
__device__ __forceinline__ void block_reduce2(float& s, float& ss, float* red) {
#pragma unroll
  for (int off = 32; off > 0; off >>= 1) {
    s += __shfl_xor(s, off);
    ss += __shfl_xor(ss, off);
  }
  const int wave = threadIdx.x >> 6;
  const int lane = threadIdx.x & 63;
  if (lane == 0) { red[wave * 2] = s; red[wave * 2 + 1] = ss; }
  __syncthreads();
  if (threadIdx.x == 0) {
    float a = 0.f, b = 0.f;
    for (int i = 0; i < 4; i++) { a += red[i * 2]; b += red[i * 2 + 1]; }
    red[0] = a; red[1] = b;
  }
  __syncthreads();
  s = red[0]; ss = red[1];
}

// ---------------- LN vit: [18432][1024] f32 -> bf16 ----------------
__global__ __launch_bounds__(256) void ln_vit_kernel(
    const float* __restrict__ x, const float* __restrict__ w,
    const float* __restrict__ b, unsigned short* __restrict__ out) {
  __shared__ float red[8];
  const int row = blockIdx.x;
  const int t = threadIdx.x;
  const float4 v = ((const float4*)(x + (size_t)row * 1024))[t];
  float s = v.x + v.y + v.z + v.w;
  float ss = v.x * v.x + v.y * v.y + v.z * v.z + v.w * v.w;
  block_reduce2(s, ss, red);
  const float m = s * (1.f / 1024.f);
  const float var = ss * (1.f / 1024.f) - m * m;
  const float rstd = rsqrtf(var + 1e-5f);
  const float4 w4 = ((const float4*)w)[t];
  const float4 b4 = ((const float4*)b)[t];
  ushort4 o;
  o.x = f2bf((v.x - m) * rstd * w4.x + b4.x);
  o.y = f2bf((v.y - m) * rstd * w4.y + b4.y);
  o.z = f2bf((v.z - m) * rstd * w4.z + b4.z);
  o.w = f2bf((v.w - m) * rstd * w4.w + b4.w);
  ((ushort4*)(out + (size_t)row * 1024))[t] = o;
}

// ================= Fused attention v4 (r13-proven, 51.9 us): 32-row tiles =================
// Grid (18, 32), 256 threads. LDS 45824 B -> 3 blocks/CU.
__global__ __launch_bounds__(256) void attfused_kernel(
    const unsigned short* __restrict__ qn, const unsigned short* __restrict__ kq,
    const unsigned short* __restrict__ vT, const float* __restrict__ qbk,
    const int* __restrict__ lengths, const float* __restrict__ vit,
    float* __restrict__ out) {
  __shared__ __align__(16) char smem[45824];
  float* Smat = (float*)smem;
  float* invr = (float*)(smem + 28672);
  float* qb_l = (float*)(smem + 28800);
  const int PB = 20480, BV = 29440;

  const int b = blockIdx.y;
  const int tm0 = blockIdx.x * 32;
  const int t = threadIdx.x;
  const int w = t >> 6, l = t & 63;
  const int lo = l & 15, hi = l >> 4;
  if (t < 128) qb_l[t] = (t < 100) ? qbk[b * 100 + t] : 0.f;

  // ---- phase A: S[32 x 128] = qn_tile @ kq^T ----
  const unsigned short* A = qn + (size_t)b * 576 * 1024;
  const unsigned short* B = kq + (size_t)b * 100 * 1024;
  const int ar = (t & 127) >> 2, ah = t >> 7, ac = (t & 3) << 3;
  const unsigned short* paA = A + (size_t)(tm0 + ar) * 1024 + ah * 32 + ac;
  const unsigned short* pbB[4];
#pragma unroll
  for (int i = 0; i < 4; i++) {
    int rb = (i & 1) * 64 + (t >> 2); if (rb > 99) rb = 99;
    pbB[i] = B + (size_t)rb * 1024 + (i >> 1) * 32 + ((t & 3) << 3);
  }
  const int cw = w << 5;

  f32x4 acc[2][2];
#pragma unroll
  for (int i = 0; i < 2; i++) { acc[i][0] = (f32x4)0.0f; acc[i][1] = (f32x4)0.0f; }

  for (int k0 = 0; k0 < 1024; k0 += 64) {
    gload16(paA + k0, smem + w * 1024);
#pragma unroll
    for (int i = 0; i < 4; i++)
      gload16(pbB[i] + k0, smem + 4096 + i * 4096 + w * 1024);
    __syncthreads();
#pragma unroll
    for (int half = 0; half < 2; half++) {
      short8 a[2], bb[2];
#pragma unroll
      for (int i = 0; i < 2; i++)
        a[i] = *(const short8*)(smem + half * 2048 + (i * 16 + lo) * 64 + hi * 16);
#pragma unroll
      for (int j = 0; j < 2; j++)
        bb[j] = *(const short8*)(smem + 4096 + half * 8192 + (cw + j * 16 + lo) * 64 + hi * 16);
#pragma unroll
      for (int i = 0; i < 2; i++)
#pragma unroll
        for (int j = 0; j < 2; j++)
          acc[i][j] = __builtin_amdgcn_mfma_f32_16x16x32_bf16(a[i], bb[j], acc[i][j], 0, 0, 0);
    }
    __syncthreads();
  }

  // ---- phase B: Smat[c][r] (stride 36) + q-bias; masked softmax (8 lanes/row) ----
#pragma unroll
  for (int i = 0; i < 2; i++) {
    const int r0 = i * 16 + hi * 4;
#pragma unroll
    for (int j = 0; j < 2; j++) {
      const int c = cw + j * 16 + lo;
      const float qb = qb_l[c];
#pragma unroll
      for (int rr = 0; rr < 4; rr++) Smat[c * 36 + r0 + rr] = acc[i][j][rr] + qb;
    }
  }
  __syncthreads();

  const int r = t >> 3, g = t & 7;
  const int len = lengths[b];
  float mx = NEG_FLT_MAX;
#pragma unroll
  for (int i = 0; i < 13; i++) {
    const int ll = g * 13 + i;
    if (ll < 100) {
      const float v = (ll < len) ? Smat[ll * 36 + r] : NEG_FLT_MAX;
      mx = fmaxf(mx, v);
    }
  }
  mx = fmaxf(mx, __shfl_xor(mx, 1));
  mx = fmaxf(mx, __shfl_xor(mx, 2));
  mx = fmaxf(mx, __shfl_xor(mx, 4));
  float sum = 0.f;
#pragma unroll
  for (int i = 0; i < 13; i++) {
    const int ll = g * 13 + i;
    if (ll < 100) {
      const float v = (ll < len) ? Smat[ll * 36 + r] : NEG_FLT_MAX;
      const float e = __expf(v - mx);
      Smat[ll * 36 + r] = e;
      sum += e;
    }
  }
  sum += __shfl_xor(sum, 1);
  sum += __shfl_xor(sum, 2);
  sum += __shfl_xor(sum, 4);
  if (g == 0) invr[r] = 1.f / sum;
  __syncthreads();

  // ---- phase C: P[32][128] bf16, swizzled ----
  {
    const float inv = invr[r];
#pragma unroll
    for (int jj = 0; jj < 4; jj++) {
      const int c0 = g * 16 + jj * 4;
      ushort4 o;
      o.x = (c0 + 0 < 100) ? f2bf(Smat[(c0 + 0) * 36 + r] * inv) : (unsigned short)0;
      o.y = (c0 + 1 < 100) ? f2bf(Smat[(c0 + 1) * 36 + r] * inv) : (unsigned short)0;
      o.z = (c0 + 2 < 100) ? f2bf(Smat[(c0 + 2) * 36 + r] * inv) : (unsigned short)0;
      o.w = (c0 + 3 < 100) ? f2bf(Smat[(c0 + 3) * 36 + r] * inv) : (unsigned short)0;
      const int phys = (r * 256 + g * 32 + jj * 8) ^ ((r & 7) << 4);
      *(ushort4*)(smem + PB + phys) = o;
    }
  }
  __syncthreads();

  // ---- phase D: out = P @ vT^T + vit; 16 N-tiles of 64 cols, half-size BsV ----
  const unsigned short* vTb = vT + (size_t)b * 131072;
  const float* vitb = vit + ((size_t)b * 576 + tm0) * 1024;
  float* outb = out + ((size_t)b * 576 + tm0) * 1024;
  const int sBcol = ((t & 15) ^ ((t >> 4) & 7)) << 3;
  for (int nt = 0; nt < 16; ++nt) {
#pragma unroll
    for (int i = 0; i < 4; i++) {
      const int vrow = nt * 64 + i * 16 + (t >> 4);
      gload16(vTb + (size_t)vrow * 128 + sBcol, smem + BV + i * 4096 + w * 1024);
    }
    __syncthreads();
    f32x4 acc2[2];
    acc2[0] = (f32x4)0.0f; acc2[1] = (f32x4)0.0f;
#pragma unroll
    for (int ks = 0; ks < 4; ks++) {
      short8 av[2], bv;
#pragma unroll
      for (int i = 0; i < 2; i++) {
        const int m = i * 16 + lo;
        av[i] = *(const short8*)(smem + PB + ((m * 256 + ks * 64 + hi * 16) ^ ((m & 7) << 4)));
      }
      const int n = (w << 4) + lo;
      bv = *(const short8*)(smem + BV + ((n * 256 + ks * 64 + hi * 16) ^ ((n & 7) << 4)));
      acc2[0] = __builtin_amdgcn_mfma_f32_16x16x32_bf16(av[0], bv, acc2[0], 0, 0, 0);
      acc2[1] = __builtin_amdgcn_mfma_f32_16x16x32_bf16(av[1], bv, acc2[1], 0, 0, 0);
    }
#pragma unroll
    for (int i = 0; i < 2; i++) {
      const int col = (w << 4) + lo;
#pragma unroll
      for (int rr = 0; rr < 4; rr++) {
        const int row = i * 16 + hi * 4 + rr;
        *(float*)(smem + ((row * 256 + col * 4) ^ ((row & 7) << 4))) = acc2[i][rr];
      }
    }
    __syncthreads();
#pragma unroll
    for (int m = 0; m < 2; m++) {
      const int row = m * 16 + (t >> 4);
      const int colb = (t & 15) * 4;
      float4 e = *(const float4*)(smem + ((row * 256 + colb * 4) ^ ((row & 7) << 4)));
      const size_t gidx = (size_t)row * 1024 + nt * 64 + colb;
      float4 vv = *(const float4*)(vitb + gidx);
      e.x += vv.x; e.y += vv.y; e.z += vv.z; e.w += vv.w;
      *(float4*)(outb + gidx) = e;
    }
    __syncthreads();
  }
}

extern "C" void kernel_launch(void* const* d_in, const int* in_sizes, int n_in,
                              void* d_out, int out_size, void* d_ws, size_t ws_size,
                              hipStream_t stream) {
  const float* vit = (const float*)d_in[0];
  const float* box = (const float*)d_in[1];
  const int* lengths = (const int*)d_in[2];
  const float* q_ln_w = (const float*)d_in[3];
  const float* q_ln_b = (const float*)d_in[4];
  const float* q_w = (const float*)d_in[5];
  const float* q_b = (const float*)d_in[6];
  const float* k_ln_w = (const float*)d_in[7];
  const float* k_ln_b = (const float*)d_in[8];
  const float* k_w = (const float*)d_in[9];
  const float* k_b = (const float*)d_in[10];
  const float* v_ln_w = (const float*)d_in[11];
  const float* v_ln_b = (const float*)d_in[12];
  const float* v_w = (const float*)d_in[13];
  const float* v_b = (const float*)d_in[14];
  float* out = (float*)d_out;
  char* ws = (char*)d_ws;

  // Arena [0, 37748736): weight/LN buffers, all dead after gemm_kv -> reused by qn.
  unsigned short* kn    = (unsigned short*)(ws + 0);          // [3200][1536]
  unsigned short* vn    = (unsigned short*)(ws + 9830400);    // [3200][1536]
  unsigned short* v_wt  = (unsigned short*)(ws + 19660800);   // [1024][1536]
  unsigned short* qwb   = (unsigned short*)(ws + 22806528);   // [1024][1024]
  unsigned short* kwb   = (unsigned short*)(ws + 24903680);   // [1536][1024] (scaled)
  unsigned short* W3    = (unsigned short*)(ws + 28049408);   // [1024][1536]
  float*          bias3 = (float*)(ws + 31195136);            // [1024]
  float*          w4    = (float*)(ws + 31199232);            // [1536]
  float*          c4    = (float*)(ws + 31207424);            // [1]
  unsigned short* qn    = (unsigned short*)(ws + 0);          // [18432][1024] (arena reuse)
  // Outside arena (live into attfused):
  float*          qbk   = (float*)(ws + 37748736);            // [3200]
  unsigned short* kq    = (unsigned short*)(ws + 37761536);   // [3200][1024]
  unsigned short* vT    = (unsigned short*)(ws + 44315136);   // [32][1024][128]

  const float scale = 0.03125f;  // 1/sqrt(1024)

  // 1. weight prep (wconv + V-transpose + wvec)
  prep_kernel<<<4737, 256, 0, stream>>>(q_w, k_w, v_w, q_b, k_b, scale,
                                        qwb, kwb, v_wt, bias3, w4, c4);

  // 2. ln_box (+fused qbk) + W3 GEMM in one grid
  mid_kernel<<<3296, 256, 0, stream>>>(box, k_ln_w, k_ln_b, v_ln_w, v_ln_b,
                                       qwb, kwb, w4, c4, kn, vn, W3, qbk);

  // 3. kq/vT projections (128x64 tiles, 800 blocks, XCD-swizzled)
  gemm_kv_kernel<<<800, 256, 0, stream>>>(kn, vn, W3, v_wt, bias3, v_b, kq, vT);

  // 4. LN vit -> qn (arena now dead)
  ln_vit_kernel<<<18432, 256, 0, stream>>>(vit, q_ln_w, q_ln_b, qn);

  // 5. fused attention: scores -> softmax -> @V -> +vit -> out
  attfused_kernel<<<dim3(18, 32), 256, 0, stream>>>(
      qn, kq, vT, qbk, lengths, vit, out);

  (void)in_sizes; (void)n_in; (void)out_size; (void)ws_size;
}

// Round 19
// 144.617 us; speedup vs baseline: 1.0968x; 1.0968x over previous
//
#include <hip/hip_runtime.h>
#include <stdint.h>

typedef __attribute__((ext_vector_type(8))) short short8;
typedef __attribute__((ext_vector_type(4))) float f32x4;

#define NEG_FLT_MAX (-3.402823466e38f)

__device__ __forceinline__ unsigned short f2bf(float f) {
  uint32_t u = __float_as_uint(f);
  uint32_t r = (u + 0x7fffu + ((u >> 16) & 1u)) >> 16;
  return (unsigned short)r;
}

__device__ __forceinline__ void gload16(const void* g, void* l) {
  __builtin_amdgcn_global_load_lds(
      (const __attribute__((address_space(1))) uint32_t*)g,
      (__attribute__((address_space(3))) uint32_t*)l, 16, 0, 0);
}

// ============ PREP: wconv (2560 blk) + V-transpose (1536 blk) + wvec (641 blk) ============
__global__ __launch_bounds__(256) void prep_kernel(
    const float* __restrict__ qw, const float* __restrict__ kw,
    const float* __restrict__ vw, const float* __restrict__ qb,
    const float* __restrict__ kb, float scale,
    unsigned short* __restrict__ qwb, unsigned short* __restrict__ kwb,
    unsigned short* __restrict__ vwt,
    float* __restrict__ bias3, float* __restrict__ w4, float* __restrict__ c4) {
  __shared__ float tile[32][33];
  const int bid = blockIdx.x;
  const int t = threadIdx.x;
  if (bid < 2560) {
    const int idx = bid * 256 + t;
    const int QG = 1024 * 1024 / 4;
    if (idx < QG) {
      float4 v = ((const float4*)qw)[idx];
      ushort4 o;
      o.x = f2bf(v.x); o.y = f2bf(v.y); o.z = f2bf(v.z); o.w = f2bf(v.w);
      ((ushort4*)qwb)[idx] = o;
    } else {
      const int j = idx - QG;
      float4 v = ((const float4*)kw)[j];
      ushort4 o;
      o.x = f2bf(v.x * scale); o.y = f2bf(v.y * scale);
      o.z = f2bf(v.z * scale); o.w = f2bf(v.w * scale);
      ((ushort4*)kwb)[j] = o;
    }
  } else if (bid < 4096) {
    const int j = bid - 2560;
    const int c0 = (j & 31) * 32, r0 = (j >> 5) * 32;
    const int tx = t & 31, ty = t >> 5;
#pragma unroll
    for (int i = ty; i < 32; i += 8)
      tile[i][tx] = vw[(size_t)(r0 + i) * 1024 + (c0 + tx)];
    __syncthreads();
#pragma unroll
    for (int i = ty; i < 32; i += 8)
      vwt[(size_t)(c0 + i) * 1536 + (r0 + tx)] = f2bf(tile[tx][i]);
  } else {
    const int idx = bid - 4096;
    const int wv = t >> 6, l = t & 63;
    float s = 0.f;
    if (idx < 256) {
      const int i = idx * 4 + wv;
      const float* row = qw + (size_t)i * 1024;
#pragma unroll
      for (int s0 = 0; s0 < 1024; s0 += 256) {
        float4 a = *(const float4*)(row + s0 + l * 4);
        float4 b = *(const float4*)(kb + s0 + l * 4);
        s += a.x * b.x + a.y * b.y + a.z * b.z + a.w * b.w;
      }
#pragma unroll
      for (int off = 32; off; off >>= 1) s += __shfl_xor(s, off);
      if (l == 0) bias3[i] = s * scale;
    } else if (idx < 640) {
      const int j = (idx - 256) * 4 + wv;
      const float* row = kw + (size_t)j * 1024;
#pragma unroll
      for (int s0 = 0; s0 < 1024; s0 += 256) {
        float4 a = *(const float4*)(row + s0 + l * 4);
        float4 b = *(const float4*)(qb + s0 + l * 4);
        s += a.x * b.x + a.y * b.y + a.z * b.z + a.w * b.w;
      }
#pragma unroll
      for (int off = 32; off; off >>= 1) s += __shfl_xor(s, off);
      if (l == 0) w4[j] = s * scale;
    } else if (wv == 0) {
#pragma unroll
      for (int s0 = 0; s0 < 1024; s0 += 256) {
        float4 a = *(const float4*)(qb + s0 + l * 4);
        float4 b = *(const float4*)(kb + s0 + l * 4);
        s += a.x * b.x + a.y * b.y + a.z * b.z + a.w * b.w;
      }
#pragma unroll
      for (int off = 32; off; off >>= 1) s += __shfl_xor(s, off);
      if (l == 0) *c4 = s * scale;
    }
  }
}

// ---------------- GEMM core, BK=64 (proven r5 structure) ----------
__device__ __forceinline__ void gemm_core64(
    const unsigned short* __restrict__ A, int lda, int rowmaxA, int tm0,
    const unsigned short* __restrict__ Bt, int ldb, int rowmaxB, int tn0,
    int K, unsigned short* As, unsigned short* Bs, f32x4 acc[4][4]) {
  const int tid = threadIdx.x;
  const int w = tid >> 6, l = tid & 63;
  const int wr = w >> 1, wc = w & 1;
  const int srow = (w << 4) + (l >> 2);
  const int scol = (l & 3) << 3;
  int ra0 = tm0 + srow;      if (ra0 > rowmaxA) ra0 = rowmaxA;
  int ra1 = tm0 + srow + 64; if (ra1 > rowmaxA) ra1 = rowmaxA;
  int rb0 = tn0 + srow;      if (rb0 > rowmaxB) rb0 = rowmaxB;
  int rb1 = tn0 + srow + 64; if (rb1 > rowmaxB) rb1 = rowmaxB;
  const unsigned short* pa0 = A + (size_t)ra0 * lda + scol;
  const unsigned short* pa1 = A + (size_t)ra1 * lda + scol;
  const unsigned short* pb0 = Bt + (size_t)rb0 * ldb + scol;
  const unsigned short* pb1 = Bt + (size_t)rb1 * ldb + scol;
  unsigned short* la0 = As + (w << 4) * 32;
  unsigned short* la1 = As + ((w << 4) + 64) * 32;
  unsigned short* lb0 = Bs + (w << 4) * 32;
  unsigned short* lb1 = Bs + ((w << 4) + 64) * 32;
  const int foff = ((l & 15) << 5) + ((l >> 4) << 3);
  const unsigned short* fa = As + (wr << 6) * 32 + foff;
  const unsigned short* fb = Bs + (wc << 6) * 32 + foff;
#pragma unroll
  for (int i = 0; i < 4; i++)
#pragma unroll
    for (int j = 0; j < 4; j++) acc[i][j] = (f32x4)0.0f;
  for (int k0 = 0; k0 < K; k0 += 64) {
    gload16(pa0 + k0, la0);
    gload16(pa1 + k0, la1);
    gload16(pb0 + k0, lb0);
    gload16(pb1 + k0, lb1);
    gload16(pa0 + k0 + 32, la0 + 4096);
    gload16(pa1 + k0 + 32, la1 + 4096);
    gload16(pb0 + k0 + 32, lb0 + 4096);
    gload16(pb1 + k0 + 32, lb1 + 4096);
    __syncthreads();
    {
      short8 a[4], b[4];
#pragma unroll
      for (int i = 0; i < 4; i++) a[i] = *(const short8*)(fa + i * 512);
#pragma unroll
      for (int j = 0; j < 4; j++) b[j] = *(const short8*)(fb + j * 512);
#pragma unroll
      for (int i = 0; i < 4; i++)
#pragma unroll
        for (int j = 0; j < 4; j++)
          acc[i][j] = __builtin_amdgcn_mfma_f32_16x16x32_bf16(a[i], b[j], acc[i][j], 0, 0, 0);
    }
    {
      short8 a[4], b[4];
#pragma unroll
      for (int i = 0; i < 4; i++) a[i] = *(const short8*)(fa + 4096 + i * 512);
#pragma unroll
      for (int j = 0; j < 4; j++) b[j] = *(const short8*)(fb + 4096 + j * 512);
#pragma unroll
      for (int i = 0; i < 4; i++)
#pragma unroll
        for (int j = 0; j < 4; j++)
          acc[i][j] = __builtin_amdgcn_mfma_f32_16x16x32_bf16(a[i], b[j], acc[i][j], 0, 0, 0);
    }
    __syncthreads();
  }
}

// ============ MID: ln_box (+fused qbk) for blocks <3200; W3 GEMM for the rest ============
__global__ __launch_bounds__(256) void mid_kernel(
    const float* __restrict__ box,
    const float* __restrict__ klnw, const float* __restrict__ klnb,
    const float* __restrict__ vlnw, const float* __restrict__ vlnb,
    const unsigned short* __restrict__ qwb, const unsigned short* __restrict__ kwb,
    const float* __restrict__ w4v, const float* __restrict__ c4,
    unsigned short* __restrict__ kn, unsigned short* __restrict__ vn,
    unsigned short* __restrict__ W3, float* __restrict__ qbk) {
  __shared__ float red[8];
  __shared__ float redq[4];
  __shared__ unsigned short As[128 * 64];
  __shared__ unsigned short Bs[128 * 64];
  const int t = threadIdx.x;
  if (blockIdx.x < 3200) {
    const int row = blockIdx.x;
    const float4* xr = (const float4*)(box + (size_t)row * 1536);
    const float4 a = xr[t];
    float4 c = make_float4(0.f, 0.f, 0.f, 0.f);
    if (t < 128) c = xr[256 + t];
    float s = a.x + a.y + a.z + a.w + c.x + c.y + c.z + c.w;
    float ss = a.x * a.x + a.y * a.y + a.z * a.z + a.w * a.w +
               c.x * c.x + c.y * c.y + c.z * c.z + c.w * c.w;
#pragma unroll
    for (int off = 32; off > 0; off >>= 1) {
      s += __shfl_xor(s, off);
      ss += __shfl_xor(ss, off);
    }
    if ((t & 63) == 0) { red[(t >> 6) * 2] = s; red[(t >> 6) * 2 + 1] = ss; }
    __syncthreads();
    if (t == 0) {
      float aa = 0.f, bb = 0.f;
      for (int i = 0; i < 4; i++) { aa += red[i * 2]; bb += red[i * 2 + 1]; }
      red[0] = aa; red[1] = bb;
    }
    __syncthreads();
    s = red[0]; ss = red[1];
    const float m = s * (1.f / 1536.f);
    const float var = ss * (1.f / 1536.f) - m * m;
    const float rstd = rsqrtf(var + 1e-5f);
    float qd;
    {
      const float4 w4 = ((const float4*)klnw)[t];
      const float4 b4 = ((const float4*)klnb)[t];
      const float k0v = (a.x - m) * rstd * w4.x + b4.x;
      const float k1v = (a.y - m) * rstd * w4.y + b4.y;
      const float k2v = (a.z - m) * rstd * w4.z + b4.z;
      const float k3v = (a.w - m) * rstd * w4.w + b4.w;
      ushort4 o;
      o.x = f2bf(k0v); o.y = f2bf(k1v); o.z = f2bf(k2v); o.w = f2bf(k3v);
      ((ushort4*)(kn + (size_t)row * 1536))[t] = o;
      const float4 wq = ((const float4*)w4v)[t];
      qd = k0v * wq.x + k1v * wq.y + k2v * wq.z + k3v * wq.w;
      const float4 w4vv = ((const float4*)vlnw)[t];
      const float4 b4vv = ((const float4*)vlnb)[t];
      o.x = f2bf((a.x - m) * rstd * w4vv.x + b4vv.x);
      o.y = f2bf((a.y - m) * rstd * w4vv.y + b4vv.y);
      o.z = f2bf((a.z - m) * rstd * w4vv.z + b4vv.z);
      o.w = f2bf((a.w - m) * rstd * w4vv.w + b4vv.w);
      ((ushort4*)(vn + (size_t)row * 1536))[t] = o;
    }
    if (t < 128) {
      const int t2 = 256 + t;
      const float4 w4 = ((const float4*)klnw)[t2];
      const float4 b4 = ((const float4*)klnb)[t2];
      const float k0v = (c.x - m) * rstd * w4.x + b4.x;
      const float k1v = (c.y - m) * rstd * w4.y + b4.y;
      const float k2v = (c.z - m) * rstd * w4.z + b4.z;
      const float k3v = (c.w - m) * rstd * w4.w + b4.w;
      ushort4 o;
      o.x = f2bf(k0v); o.y = f2bf(k1v); o.z = f2bf(k2v); o.w = f2bf(k3v);
      ((ushort4*)(kn + (size_t)row * 1536))[t2] = o;
      const float4 wq = ((const float4*)w4v)[t2];
      qd += k0v * wq.x + k1v * wq.y + k2v * wq.z + k3v * wq.w;
      const float4 w4vv = ((const float4*)vlnw)[t2];
      const float4 b4vv = ((const float4*)vlnb)[t2];
      o.x = f2bf((c.x - m) * rstd * w4vv.x + b4vv.x);
      o.y = f2bf((c.y - m) * rstd * w4vv.y + b4vv.y);
      o.z = f2bf((c.z - m) * rstd * w4vv.z + b4vv.z);
      o.w = f2bf((c.w - m) * rstd * w4vv.w + b4vv.w);
      ((ushort4*)(vn + (size_t)row * 1536))[t2] = o;
    }
#pragma unroll
    for (int off = 32; off; off >>= 1) qd += __shfl_xor(qd, off);
    if ((t & 63) == 0) redq[t >> 6] = qd;
    __syncthreads();
    if (t == 0) qbk[row] = redq[0] + redq[1] + redq[2] + redq[3] + c4[0];
  } else {
    const int j = blockIdx.x - 3200;
    const int tm0 = (j & 7) * 128, tn0 = (j >> 3) * 128;
    f32x4 acc[4][4];
    gemm_core64(qwb, 1024, 1023, tm0, kwb, 1024, 1535, tn0, 1024, As, Bs, acc);
    const int w = t >> 6, l = t & 63;
    const int wr = w >> 1, wc = w & 1;
#pragma unroll
    for (int i = 0; i < 4; i++) {
      const int row0 = tm0 + wr * 64 + i * 16 + (l >> 4) * 4;
#pragma unroll
      for (int jj = 0; jj < 4; jj++) {
        const int col = tn0 + wc * 64 + jj * 16 + (l & 15);
#pragma unroll
        for (int r = 0; r < 4; r++)
          W3[(size_t)(row0 + r) * 1536 + col] = f2bf(acc[i][jj][r]);
      }
    }
  }
}

// ---------------- kq + vT projections, XCD-swizzled 1D grid (400 blocks) ----------------
__global__ __launch_bounds__(256) void gemm_kv_kernel(
    const unsigned short* __restrict__ kn, const unsigned short* __restrict__ vn,
    const unsigned short* __restrict__ W3, const unsigned short* __restrict__ vwt,
    const float* __restrict__ bias3, const float* __restrict__ vb,
    unsigned short* __restrict__ kq, unsigned short* __restrict__ vT) {
  __shared__ unsigned short As[128 * 64];
  __shared__ unsigned short Bs[128 * 64];
  const int id = blockIdx.x;
  const int sw = (id & 7) * 50 + (id >> 3);
  const int z = sw / 200;
  const int rem = sw - z * 200;
  const int tm0 = (rem % 25) * 128, tn0 = (rem / 25) * 128;
  const unsigned short* A = z ? vn : kn;
  const unsigned short* Bt = z ? vwt : W3;
  const float* bias = z ? vb : bias3;
  f32x4 acc[4][4];
  gemm_core64(A, 1536, 3199, tm0, Bt, 1536, 1023, tn0, 1536, As, Bs, acc);
  const int tid = threadIdx.x;
  const int w = tid >> 6, l = tid & 63;
  const int wr = w >> 1, wc = w & 1;
#pragma unroll
  for (int i = 0; i < 4; i++) {
    const int row0 = tm0 + wr * 64 + i * 16 + (l >> 4) * 4;
#pragma unroll
    for (int j = 0; j < 4; j++) {
      const int col = tn0 + wc * 64 + j * 16 + (l & 15);
      const float bv = bias[col];
#pragma unroll
      for (int r = 0; r < 4; r++) {
        const int row = row0 + r;
        const float val = acc[i][j][r] + bv;
        if (!z) {
          kq[(size_t)row * 1024 + col] = f2bf(val);
        } else {
          const int bb = row / 100;
          const int ll = row - bb * 100;
          vT[((size_t)bb * 1024 + col) * 128 + ll] = f2bf(val);
        }
      }
    }
  }
}

// ---------------- block reduction helper ----------------
__device__ __forceinline__ void block_reduce2(float& s, float& ss, float* red) {
#pragma unroll
  for (int off = 32; off > 0; off >>= 1) {
    s += __shfl_xor(s, off);
    ss += __shfl_xor(ss, off);
  }
  const int wave = threadIdx.x >> 6;
  const int lane = threadIdx.x & 63;
  if (lane == 0) { red[wave * 2] = s; red[wave * 2 + 1] = ss; }
  __syncthreads();
  if (threadIdx.x == 0) {
    float a = 0.f, b = 0.f;
    for (int i = 0; i < 4; i++) { a += red[i * 2]; b += red[i * 2 + 1]; }
    red[0] = a; red[1] = b;
  }
  __syncthreads();
  s = red[0]; ss = red[1];
}

// ---------------- LN vit: [18432][1024] f32 -> bf16 ----------------
__global__ __launch_bounds__(256) void ln_vit_kernel(
    const float* __restrict__ x, const float* __restrict__ w,
    const float* __restrict__ b, unsigned short* __restrict__ out) {
  __shared__ float red[8];
  const int row = blockIdx.x;
  const int t = threadIdx.x;
  const float4 v = ((const float4*)(x + (size_t)row * 1024))[t];
  float s = v.x + v.y + v.z + v.w;
  float ss = v.x * v.x + v.y * v.y + v.z * v.z + v.w * v.w;
  block_reduce2(s, ss, red);
  const float m = s * (1.f / 1024.f);
  const float var = ss * (1.f / 1024.f) - m * m;
  const float rstd = rsqrtf(var + 1e-5f);
  const float4 w4 = ((const float4*)w)[t];
  const float4 b4 = ((const float4*)b)[t];
  ushort4 o;
  o.x = f2bf((v.x - m) * rstd * w4.x + b4.x);
  o.y = f2bf((v.y - m) * rstd * w4.y + b4.y);
  o.z = f2bf((v.z - m) * rstd * w4.z + b4.z);
  o.w = f2bf((v.w - m) * rstd * w4.w + b4.w);
  ((ushort4*)(out + (size_t)row * 1024))[t] = o;
}

// ================= Fused attention v4 (r13-proven) + bijective XCD swizzle =================
// Grid 576 (=8*72), 256 threads. LDS 45824 B -> 3 blocks/CU.
__global__ __launch_bounds__(256) void attfused_kernel(
    const unsigned short* __restrict__ qn, const unsigned short* __restrict__ kq,
    const unsigned short* __restrict__ vT, const float* __restrict__ qbk,
    const int* __restrict__ lengths, const float* __restrict__ vit,
    float* __restrict__ out) {
  __shared__ __align__(16) char smem[45824];
  float* Smat = (float*)smem;
  float* invr = (float*)(smem + 28672);
  float* qb_l = (float*)(smem + 28800);
  const int PB = 20480, BV = 29440;

  // bijective XCD swizzle: 576 = 8 * 72; each XCD gets 72 consecutive work items (4 batches)
  const int id = blockIdx.x;
  const int swz = (id & 7) * 72 + (id >> 3);
  const int b = swz / 18;
  const int tm0 = (swz - b * 18) * 32;
  const int t = threadIdx.x;
  const int w = t >> 6, l = t & 63;
  const int lo = l & 15, hi = l >> 4;
  if (t < 128) qb_l[t] = (t < 100) ? qbk[b * 100 + t] : 0.f;

  // ---- phase A: S[32 x 128] = qn_tile @ kq^T ----
  const unsigned short* A = qn + (size_t)b * 576 * 1024;
  const unsigned short* B = kq + (size_t)b * 100 * 1024;
  const int ar = (t & 127) >> 2, ah = t >> 7, ac = (t & 3) << 3;
  const unsigned short* paA = A + (size_t)(tm0 + ar) * 1024 + ah * 32 + ac;
  const unsigned short* pbB[4];
#pragma unroll
  for (int i = 0; i < 4; i++) {
    int rb = (i & 1) * 64 + (t >> 2); if (rb > 99) rb = 99;
    pbB[i] = B + (size_t)rb * 1024 + (i >> 1) * 32 + ((t & 3) << 3);
  }
  const int cw = w << 5;

  f32x4 acc[2][2];
#pragma unroll
  for (int i = 0; i < 2; i++) { acc[i][0] = (f32x4)0.0f; acc[i][1] = (f32x4)0.0f; }

  for (int k0 = 0; k0 < 1024; k0 += 64) {
    gload16(paA + k0, smem + w * 1024);
#pragma unroll
    for (int i = 0; i < 4; i++)
      gload16(pbB[i] + k0, smem + 4096 + i * 4096 + w * 1024);
    __syncthreads();
#pragma unroll
    for (int half = 0; half < 2; half++) {
      short8 a[2], bb[2];
#pragma unroll
      for (int i = 0; i < 2; i++)
        a[i] = *(const short8*)(smem + half * 2048 + (i * 16 + lo) * 64 + hi * 16);
#pragma unroll
      for (int j = 0; j < 2; j++)
        bb[j] = *(const short8*)(smem + 4096 + half * 8192 + (cw + j * 16 + lo) * 64 + hi * 16);
#pragma unroll
      for (int i = 0; i < 2; i++)
#pragma unroll
        for (int j = 0; j < 2; j++)
          acc[i][j] = __builtin_amdgcn_mfma_f32_16x16x32_bf16(a[i], bb[j], acc[i][j], 0, 0, 0);
    }
    __syncthreads();
  }

  // ---- phase B: Smat[c][r] (stride 36) + q-bias; masked softmax (8 lanes/row) ----
#pragma unroll
  for (int i = 0; i < 2; i++) {
    const int r0 = i * 16 + hi * 4;
#pragma unroll
    for (int j = 0; j < 2; j++) {
      const int c = cw + j * 16 + lo;
      const float qb = qb_l[c];
#pragma unroll
      for (int rr = 0; rr < 4; rr++) Smat[c * 36 + r0 + rr] = acc[i][j][rr] + qb;
    }
  }
  __syncthreads();

  const int r = t >> 3, g = t & 7;
  const int len = lengths[b];
  float mx = NEG_FLT_MAX;
#pragma unroll
  for (int i = 0; i < 13; i++) {
    const int ll = g * 13 + i;
    if (ll < 100) {
      const float v = (ll < len) ? Smat[ll * 36 + r] : NEG_FLT_MAX;
      mx = fmaxf(mx, v);
    }
  }
  mx = fmaxf(mx, __shfl_xor(mx, 1));
  mx = fmaxf(mx, __shfl_xor(mx, 2));
  mx = fmaxf(mx, __shfl_xor(mx, 4));
  float sum = 0.f;
#pragma unroll
  for (int i = 0; i < 13; i++) {
    const int ll = g * 13 + i;
    if (ll < 100) {
      const float v = (ll < len) ? Smat[ll * 36 + r] : NEG_FLT_MAX;
      const float e = __expf(v - mx);
      Smat[ll * 36 + r] = e;
      sum += e;
    }
  }
  sum += __shfl_xor(sum, 1);
  sum += __shfl_xor(sum, 2);
  sum += __shfl_xor(sum, 4);
  if (g == 0) invr[r] = 1.f / sum;
  __syncthreads();

  // ---- phase C: P[32][128] bf16, swizzled ----
  {
    const float inv = invr[r];
#pragma unroll
    for (int jj = 0; jj < 4; jj++) {
      const int c0 = g * 16 + jj * 4;
      ushort4 o;
      o.x = (c0 + 0 < 100) ? f2bf(Smat[(c0 + 0) * 36 + r] * inv) : (unsigned short)0;
      o.y = (c0 + 1 < 100) ? f2bf(Smat[(c0 + 1) * 36 + r] * inv) : (unsigned short)0;
      o.z = (c0 + 2 < 100) ? f2bf(Smat[(c0 + 2) * 36 + r] * inv) : (unsigned short)0;
      o.w = (c0 + 3 < 100) ? f2bf(Smat[(c0 + 3) * 36 + r] * inv) : (unsigned short)0;
      const int phys = (r * 256 + g * 32 + jj * 8) ^ ((r & 7) << 4);
      *(ushort4*)(smem + PB + phys) = o;
    }
  }
  __syncthreads();

  // ---- phase D: out = P @ vT^T + vit; 16 N-tiles of 64 cols ----
  const unsigned short* vTb = vT + (size_t)b * 131072;
  const float* vitb = vit + ((size_t)b * 576 + tm0) * 1024;
  float* outb = out + ((size_t)b * 576 + tm0) * 1024;
  const int sBcol = ((t & 15) ^ ((t >> 4) & 7)) << 3;
  for (int nt = 0; nt < 16; ++nt) {
#pragma unroll
    for (int i = 0; i < 4; i++) {
      const int vrow = nt * 64 + i * 16 + (t >> 4);
      gload16(vTb + (size_t)vrow * 128 + sBcol, smem + BV + i * 4096 + w * 1024);
    }
    __syncthreads();
    f32x4 acc2[2];
    acc2[0] = (f32x4)0.0f; acc2[1] = (f32x4)0.0f;
#pragma unroll
    for (int ks = 0; ks < 4; ks++) {
      short8 av[2], bv;
#pragma unroll
      for (int i = 0; i < 2; i++) {
        const int m = i * 16 + lo;
        av[i] = *(const short8*)(smem + PB + ((m * 256 + ks * 64 + hi * 16) ^ ((m & 7) << 4)));
      }
      const int n = (w << 4) + lo;
      bv = *(const short8*)(smem + BV + ((n * 256 + ks * 64 + hi * 16) ^ ((n & 7) << 4)));
      acc2[0] = __builtin_amdgcn_mfma_f32_16x16x32_bf16(av[0], bv, acc2[0], 0, 0, 0);
      acc2[1] = __builtin_amdgcn_mfma_f32_16x16x32_bf16(av[1], bv, acc2[1], 0, 0, 0);
    }
#pragma unroll
    for (int i = 0; i < 2; i++) {
      const int col = (w << 4) + lo;
#pragma unroll
      for (int rr = 0; rr < 4; rr++) {
        const int row = i * 16 + hi * 4 + rr;
        *(float*)(smem + ((row * 256 + col * 4) ^ ((row & 7) << 4))) = acc2[i][rr];
      }
    }
    __syncthreads();
#pragma unroll
    for (int m = 0; m < 2; m++) {
      const int row = m * 16 + (t >> 4);
      const int colb = (t & 15) * 4;
      float4 e = *(const float4*)(smem + ((row * 256 + colb * 4) ^ ((row & 7) << 4)));
      const size_t gidx = (size_t)row * 1024 + nt * 64 + colb;
      float4 vv = *(const float4*)(vitb + gidx);
      e.x += vv.x; e.y += vv.y; e.z += vv.z; e.w += vv.w;
      *(float4*)(outb + gidx) = e;
    }
    __syncthreads();
  }
}

extern "C" void kernel_launch(void* const* d_in, const int* in_sizes, int n_in,
                              void* d_out, int out_size, void* d_ws, size_t ws_size,
                              hipStream_t stream) {
  const float* vit = (const float*)d_in[0];
  const float* box = (const float*)d_in[1];
  const int* lengths = (const int*)d_in[2];
  const float* q_ln_w = (const float*)d_in[3];
  const float* q_ln_b = (const float*)d_in[4];
  const float* q_w = (const float*)d_in[5];
  const float* q_b = (const float*)d_in[6];
  const float* k_ln_w = (const float*)d_in[7];
  const float* k_ln_b = (const float*)d_in[8];
  const float* k_w = (const float*)d_in[9];
  const float* k_b = (const float*)d_in[10];
  const float* v_ln_w = (const float*)d_in[11];
  const float* v_ln_b = (const float*)d_in[12];
  const float* v_w = (const float*)d_in[13];
  const float* v_b = (const float*)d_in[14];
  float* out = (float*)d_out;
  char* ws = (char*)d_ws;

  // Arena [0, 37748736): weight/LN buffers, all dead after gemm_kv -> reused by qn.
  unsigned short* kn    = (unsigned short*)(ws + 0);          // [3200][1536]
  unsigned short* vn    = (unsigned short*)(ws + 9830400);    // [3200][1536]
  unsigned short* v_wt  = (unsigned short*)(ws + 19660800);   // [1024][1536]
  unsigned short* qwb   = (unsigned short*)(ws + 22806528);   // [1024][1024]
  unsigned short* kwb   = (unsigned short*)(ws + 24903680);   // [1536][1024] (scaled)
  unsigned short* W3    = (unsigned short*)(ws + 28049408);   // [1024][1536]
  float*          bias3 = (float*)(ws + 31195136);            // [1024]
  float*          w4    = (float*)(ws + 31199232);            // [1536]
  float*          c4    = (float*)(ws + 31207424);            // [1]
  unsigned short* qn    = (unsigned short*)(ws + 0);          // [18432][1024] (arena reuse)
  // Outside arena (live into attfused):
  float*          qbk   = (float*)(ws + 37748736);            // [3200]
  unsigned short* kq    = (unsigned short*)(ws + 37761536);   // [3200][1024]
  unsigned short* vT    = (unsigned short*)(ws + 44315136);   // [32][1024][128]

  const float scale = 0.03125f;  // 1/sqrt(1024)

  // 1. weight prep (wconv + V-transpose + wvec)
  prep_kernel<<<4737, 256, 0, stream>>>(q_w, k_w, v_w, q_b, k_b, scale,
                                        qwb, kwb, v_wt, bias3, w4, c4);

  // 2. ln_box (+fused qbk) + W3 GEMM in one grid
  mid_kernel<<<3296, 256, 0, stream>>>(box, k_ln_w, k_ln_b, v_ln_w, v_ln_b,
                                       qwb, kwb, w4, c4, kn, vn, W3, qbk);

  // 3. kq/vT projections (128x128 tiles, 400 blocks, XCD-swizzled)
  gemm_kv_kernel<<<400, 256, 0, stream>>>(kn, vn, W3, v_wt, bias3, v_b, kq, vT);

  // 4. LN vit -> qn (arena now dead)
  ln_vit_kernel<<<18432, 256, 0, stream>>>(vit, q_ln_w, q_ln_b, qn);

  // 5. fused attention: scores -> softmax -> @V -> +vit -> out (XCD-swizzled grid)
  attfused_kernel<<<576, 256, 0, stream>>>(
      qn, kq, vT, qbk, lengths, vit, out);

  (void)in_sizes; (void)n_in; (void)out_size; (void)ws_size;
}

// Round 20
// 142.783 us; speedup vs baseline: 1.1109x; 1.0128x over previous
//
#include <hip/hip_runtime.h>
#include <stdint.h>

typedef __attribute__((ext_vector_type(8))) short short8;
typedef __attribute__((ext_vector_type(4))) float f32x4;

#define NEG_FLT_MAX (-3.402823466e38f)

__device__ __forceinline__ unsigned short f2bf(float f) {
  uint32_t u = __float_as_uint(f);
  uint32_t r = (u + 0x7fffu + ((u >> 16) & 1u)) >> 16;
  return (unsigned short)r;
}

__device__ __forceinline__ void gload16(const void* g, void* l) {
  __builtin_amdgcn_global_load_lds(
      (const __attribute__((address_space(1))) uint32_t*)g,
      (__attribute__((address_space(3))) uint32_t*)l, 16, 0, 0);
}

// ============ PREP: wconv (2560 blk) + V-transpose (1536 blk) + wvec (641 blk) ============
__global__ __launch_bounds__(256) void prep_kernel(
    const float* __restrict__ qw, const float* __restrict__ kw,
    const float* __restrict__ vw, const float* __restrict__ qb,
    const float* __restrict__ kb, float scale,
    unsigned short* __restrict__ qwb, unsigned short* __restrict__ kwb,
    unsigned short* __restrict__ vwt,
    float* __restrict__ bias3, float* __restrict__ w4, float* __restrict__ c4) {
  __shared__ float tile[32][33];
  const int bid = blockIdx.x;
  const int t = threadIdx.x;
  if (bid < 2560) {
    const int idx = bid * 256 + t;
    const int QG = 1024 * 1024 / 4;
    if (idx < QG) {
      float4 v = ((const float4*)qw)[idx];
      ushort4 o;
      o.x = f2bf(v.x); o.y = f2bf(v.y); o.z = f2bf(v.z); o.w = f2bf(v.w);
      ((ushort4*)qwb)[idx] = o;
    } else {
      const int j = idx - QG;
      float4 v = ((const float4*)kw)[j];
      ushort4 o;
      o.x = f2bf(v.x * scale); o.y = f2bf(v.y * scale);
      o.z = f2bf(v.z * scale); o.w = f2bf(v.w * scale);
      ((ushort4*)kwb)[j] = o;
    }
  } else if (bid < 4096) {
    const int j = bid - 2560;
    const int c0 = (j & 31) * 32, r0 = (j >> 5) * 32;
    const int tx = t & 31, ty = t >> 5;
#pragma unroll
    for (int i = ty; i < 32; i += 8)
      tile[i][tx] = vw[(size_t)(r0 + i) * 1024 + (c0 + tx)];
    __syncthreads();
#pragma unroll
    for (int i = ty; i < 32; i += 8)
      vwt[(size_t)(c0 + i) * 1536 + (r0 + tx)] = f2bf(tile[tx][i]);
  } else {
    const int idx = bid - 4096;
    const int wv = t >> 6, l = t & 63;
    float s = 0.f;
    if (idx < 256) {
      const int i = idx * 4 + wv;
      const float* row = qw + (size_t)i * 1024;
#pragma unroll
      for (int s0 = 0; s0 < 1024; s0 += 256) {
        float4 a = *(const float4*)(row + s0 + l * 4);
        float4 b = *(const float4*)(kb + s0 + l * 4);
        s += a.x * b.x + a.y * b.y + a.z * b.z + a.w * b.w;
      }
#pragma unroll
      for (int off = 32; off; off >>= 1) s += __shfl_xor(s, off);
      if (l == 0) bias3[i] = s * scale;
    } else if (idx < 640) {
      const int j = (idx - 256) * 4 + wv;
      const float* row = kw + (size_t)j * 1024;
#pragma unroll
      for (int s0 = 0; s0 < 1024; s0 += 256) {
        float4 a = *(const float4*)(row + s0 + l * 4);
        float4 b = *(const float4*)(qb + s0 + l * 4);
        s += a.x * b.x + a.y * b.y + a.z * b.z + a.w * b.w;
      }
#pragma unroll
      for (int off = 32; off; off >>= 1) s += __shfl_xor(s, off);
      if (l == 0) w4[j] = s * scale;
    } else if (wv == 0) {
#pragma unroll
      for (int s0 = 0; s0 < 1024; s0 += 256) {
        float4 a = *(const float4*)(qb + s0 + l * 4);
        float4 b = *(const float4*)(kb + s0 + l * 4);
        s += a.x * b.x + a.y * b.y + a.z * b.z + a.w * b.w;
      }
#pragma unroll
      for (int off = 32; off; off >>= 1) s += __shfl_xor(s, off);
      if (l == 0) *c4 = s * scale;
    }
  }
}

// ---------------- GEMM core, BK=64 (proven r5 structure; used by mid's W3) ----------
__device__ __forceinline__ void gemm_core64(
    const unsigned short* __restrict__ A, int lda, int rowmaxA, int tm0,
    const unsigned short* __restrict__ Bt, int ldb, int rowmaxB, int tn0,
    int K, unsigned short* As, unsigned short* Bs, f32x4 acc[4][4]) {
  const int tid = threadIdx.x;
  const int w = tid >> 6, l = tid & 63;
  const int wr = w >> 1, wc = w & 1;
  const int srow = (w << 4) + (l >> 2);
  const int scol = (l & 3) << 3;
  int ra0 = tm0 + srow;      if (ra0 > rowmaxA) ra0 = rowmaxA;
  int ra1 = tm0 + srow + 64; if (ra1 > rowmaxA) ra1 = rowmaxA;
  int rb0 = tn0 + srow;      if (rb0 > rowmaxB) rb0 = rowmaxB;
  int rb1 = tn0 + srow + 64; if (rb1 > rowmaxB) rb1 = rowmaxB;
  const unsigned short* pa0 = A + (size_t)ra0 * lda + scol;
  const unsigned short* pa1 = A + (size_t)ra1 * lda + scol;
  const unsigned short* pb0 = Bt + (size_t)rb0 * ldb + scol;
  const unsigned short* pb1 = Bt + (size_t)rb1 * ldb + scol;
  unsigned short* la0 = As + (w << 4) * 32;
  unsigned short* la1 = As + ((w << 4) + 64) * 32;
  unsigned short* lb0 = Bs + (w << 4) * 32;
  unsigned short* lb1 = Bs + ((w << 4) + 64) * 32;
  const int foff = ((l & 15) << 5) + ((l >> 4) << 3);
  const unsigned short* fa = As + (wr << 6) * 32 + foff;
  const unsigned short* fb = Bs + (wc << 6) * 32 + foff;
#pragma unroll
  for (int i = 0; i < 4; i++)
#pragma unroll
    for (int j = 0; j < 4; j++) acc[i][j] = (f32x4)0.0f;
  for (int k0 = 0; k0 < K; k0 += 64) {
    gload16(pa0 + k0, la0);
    gload16(pa1 + k0, la1);
    gload16(pb0 + k0, lb0);
    gload16(pb1 + k0, lb1);
    gload16(pa0 + k0 + 32, la0 + 4096);
    gload16(pa1 + k0 + 32, la1 + 4096);
    gload16(pb0 + k0 + 32, lb0 + 4096);
    gload16(pb1 + k0 + 32, lb1 + 4096);
    __syncthreads();
    {
      short8 a[4], b[4];
#pragma unroll
      for (int i = 0; i < 4; i++) a[i] = *(const short8*)(fa + i * 512);
#pragma unroll
      for (int j = 0; j < 4; j++) b[j] = *(const short8*)(fb + j * 512);
#pragma unroll
      for (int i = 0; i < 4; i++)
#pragma unroll
        for (int j = 0; j < 4; j++)
          acc[i][j] = __builtin_amdgcn_mfma_f32_16x16x32_bf16(a[i], b[j], acc[i][j], 0, 0, 0);
    }
    {
      short8 a[4], b[4];
#pragma unroll
      for (int i = 0; i < 4; i++) a[i] = *(const short8*)(fa + 4096 + i * 512);
#pragma unroll
      for (int j = 0; j < 4; j++) b[j] = *(const short8*)(fb + 4096 + j * 512);
#pragma unroll
      for (int i = 0; i < 4; i++)
#pragma unroll
        for (int j = 0; j < 4; j++)
          acc[i][j] = __builtin_amdgcn_mfma_f32_16x16x32_bf16(a[i], b[j], acc[i][j], 0, 0, 0);
    }
    __syncthreads();
  }
}

// ======== GEMM core, BK=64, double-buffered (r6-proven, for grid-bound gemm_kv) ========
// LDS: As,Bs each [2 buf][2 khalf][128][32] bf16 (32 KB each, 64 KB total).
__device__ __forceinline__ void gemm_core_db(
    const unsigned short* __restrict__ A, int lda, int rowmaxA, int tm0,
    const unsigned short* __restrict__ Bt, int ldb, int rowmaxB, int tn0,
    int K, unsigned short* As, unsigned short* Bs, f32x4 acc[4][4]) {
  const int tid = threadIdx.x;
  const int w = tid >> 6, l = tid & 63;
  const int wr = w >> 1, wc = w & 1;
  const int srow = (w << 4) + (l >> 2);
  const int scol = (l & 3) << 3;
  int ra0 = tm0 + srow;      if (ra0 > rowmaxA) ra0 = rowmaxA;
  int ra1 = tm0 + srow + 64; if (ra1 > rowmaxA) ra1 = rowmaxA;
  int rb0 = tn0 + srow;      if (rb0 > rowmaxB) rb0 = rowmaxB;
  int rb1 = tn0 + srow + 64; if (rb1 > rowmaxB) rb1 = rowmaxB;
  const unsigned short* pa0 = A + (size_t)ra0 * lda + scol;
  const unsigned short* pa1 = A + (size_t)ra1 * lda + scol;
  const unsigned short* pb0 = Bt + (size_t)rb0 * ldb + scol;
  const unsigned short* pb1 = Bt + (size_t)rb1 * ldb + scol;
  unsigned short* la0 = As + (w << 4) * 32;
  unsigned short* la1 = As + ((w << 4) + 64) * 32;
  unsigned short* lb0 = Bs + (w << 4) * 32;
  unsigned short* lb1 = Bs + ((w << 4) + 64) * 32;
  const int faoff = (wr << 6) * 32 + ((l & 15) << 5) + ((l >> 4) << 3);
  const int fboff = (wc << 6) * 32 + ((l & 15) << 5) + ((l >> 4) << 3);
#pragma unroll
  for (int i = 0; i < 4; i++)
#pragma unroll
    for (int j = 0; j < 4; j++) acc[i][j] = (f32x4)0.0f;

#define STAGE8(k0, bo) do {                                                  \
    gload16(pa0 + (k0), la0 + (bo));                                         \
    gload16(pa1 + (k0), la1 + (bo));                                         \
    gload16(pb0 + (k0), lb0 + (bo));                                         \
    gload16(pb1 + (k0), lb1 + (bo));                                         \
    gload16(pa0 + (k0) + 32, la0 + (bo) + 4096);                             \
    gload16(pa1 + (k0) + 32, la1 + (bo) + 4096);                             \
    gload16(pb0 + (k0) + 32, lb0 + (bo) + 4096);                             \
    gload16(pb1 + (k0) + 32, lb1 + (bo) + 4096);                             \
  } while (0)

  STAGE8(0, 0);
  __syncthreads();
  int p = 0;
  for (int k0 = 0; k0 < K; k0 += 64) {
    if (k0 + 64 < K) STAGE8(k0 + 64, (p ^ 1) * 8192);
    const unsigned short* fa = As + p * 8192 + faoff;
    const unsigned short* fb = Bs + p * 8192 + fboff;
    {
      short8 a[4], b[4];
#pragma unroll
      for (int i = 0; i < 4; i++) a[i] = *(const short8*)(fa + i * 512);
#pragma unroll
      for (int j = 0; j < 4; j++) b[j] = *(const short8*)(fb + j * 512);
#pragma unroll
      for (int i = 0; i < 4; i++)
#pragma unroll
        for (int j = 0; j < 4; j++)
          acc[i][j] = __builtin_amdgcn_mfma_f32_16x16x32_bf16(a[i], b[j], acc[i][j], 0, 0, 0);
    }
    {
      short8 a[4], b[4];
#pragma unroll
      for (int i = 0; i < 4; i++) a[i] = *(const short8*)(fa + 4096 + i * 512);
#pragma unroll
      for (int j = 0; j < 4; j++) b[j] = *(const short8*)(fb + 4096 + j * 512);
#pragma unroll
      for (int i = 0; i < 4; i++)
#pragma unroll
        for (int j = 0; j < 4; j++)
          acc[i][j] = __builtin_amdgcn_mfma_f32_16x16x32_bf16(a[i], b[j], acc[i][j], 0, 0, 0);
    }
    __syncthreads();
    p ^= 1;
  }
#undef STAGE8
}

// ============ MID: ln_box (+fused qbk) for blocks <3200; W3 GEMM for the rest ============
__global__ __launch_bounds__(256) void mid_kernel(
    const float* __restrict__ box,
    const float* __restrict__ klnw, const float* __restrict__ klnb,
    const float* __restrict__ vlnw, const float* __restrict__ vlnb,
    const unsigned short* __restrict__ qwb, const unsigned short* __restrict__ kwb,
    const float* __restrict__ w4v, const float* __restrict__ c4,
    unsigned short* __restrict__ kn, unsigned short* __restrict__ vn,
    unsigned short* __restrict__ W3, float* __restrict__ qbk) {
  __shared__ float red[8];
  __shared__ float redq[4];
  __shared__ unsigned short As[128 * 64];
  __shared__ unsigned short Bs[128 * 64];
  const int t = threadIdx.x;
  if (blockIdx.x < 3200) {
    const int row = blockIdx.x;
    const float4* xr = (const float4*)(box + (size_t)row * 1536);
    const float4 a = xr[t];
    float4 c = make_float4(0.f, 0.f, 0.f, 0.f);
    if (t < 128) c = xr[256 + t];
    float s = a.x + a.y + a.z + a.w + c.x + c.y + c.z + c.w;
    float ss = a.x * a.x + a.y * a.y + a.z * a.z + a.w * a.w +
               c.x * c.x + c.y * c.y + c.z * c.z + c.w * c.w;
#pragma unroll
    for (int off = 32; off > 0; off >>= 1) {
      s += __shfl_xor(s, off);
      ss += __shfl_xor(ss, off);
    }
    if ((t & 63) == 0) { red[(t >> 6) * 2] = s; red[(t >> 6) * 2 + 1] = ss; }
    __syncthreads();
    if (t == 0) {
      float aa = 0.f, bb = 0.f;
      for (int i = 0; i < 4; i++) { aa += red[i * 2]; bb += red[i * 2 + 1]; }
      red[0] = aa; red[1] = bb;
    }
    __syncthreads();
    s = red[0]; ss = red[1];
    const float m = s * (1.f / 1536.f);
    const float var = ss * (1.f / 1536.f) - m * m;
    const float rstd = rsqrtf(var + 1e-5f);
    float qd;
    {
      const float4 w4 = ((const float4*)klnw)[t];
      const float4 b4 = ((const float4*)klnb)[t];
      const float k0v = (a.x - m) * rstd * w4.x + b4.x;
      const float k1v = (a.y - m) * rstd * w4.y + b4.y;
      const float k2v = (a.z - m) * rstd * w4.z + b4.z;
      const float k3v = (a.w - m) * rstd * w4.w + b4.w;
      ushort4 o;
      o.x = f2bf(k0v); o.y = f2bf(k1v); o.z = f2bf(k2v); o.w = f2bf(k3v);
      ((ushort4*)(kn + (size_t)row * 1536))[t] = o;
      const float4 wq = ((const float4*)w4v)[t];
      qd = k0v * wq.x + k1v * wq.y + k2v * wq.z + k3v * wq.w;
      const float4 w4vv = ((const float4*)vlnw)[t];
      const float4 b4vv = ((const float4*)vlnb)[t];
      o.x = f2bf((a.x - m) * rstd * w4vv.x + b4vv.x);
      o.y = f2bf((a.y - m) * rstd * w4vv.y + b4vv.y);
      o.z = f2bf((a.z - m) * rstd * w4vv.z + b4vv.z);
      o.w = f2bf((a.w - m) * rstd * w4vv.w + b4vv.w);
      ((ushort4*)(vn + (size_t)row * 1536))[t] = o;
    }
    if (t < 128) {
      const int t2 = 256 + t;
      const float4 w4 = ((const float4*)klnw)[t2];
      const float4 b4 = ((const float4*)klnb)[t2];
      const float k0v = (c.x - m) * rstd * w4.x + b4.x;
      const float k1v = (c.y - m) * rstd * w4.y + b4.y;
      const float k2v = (c.z - m) * rstd * w4.z + b4.z;
      const float k3v = (c.w - m) * rstd * w4.w + b4.w;
      ushort4 o;
      o.x = f2bf(k0v); o.y = f2bf(k1v); o.z = f2bf(k2v); o.w = f2bf(k3v);
      ((ushort4*)(kn + (size_t)row * 1536))[t2] = o;
      const float4 wq = ((const float4*)w4v)[t2];
      qd += k0v * wq.x + k1v * wq.y + k2v * wq.z + k3v * wq.w;
      const float4 w4vv = ((const float4*)vlnw)[t2];
      const float4 b4vv = ((const float4*)vlnb)[t2];
      o.x = f2bf((c.x - m) * rstd * w4vv.x + b4vv.x);
      o.y = f2bf((c.y - m) * rstd * w4vv.y + b4vv.y);
      o.z = f2bf((c.z - m) * rstd * w4vv.z + b4vv.z);
      o.w = f2bf((c.w - m) * rstd * w4vv.w + b4vv.w);
      ((ushort4*)(vn + (size_t)row * 1536))[t2] = o;
    }
#pragma unroll
    for (int off = 32; off; off >>= 1) qd += __shfl_xor(qd, off);
    if ((t & 63) == 0) redq[t >> 6] = qd;
    __syncthreads();
    if (t == 0) qbk[row] = redq[0] + redq[1] + redq[2] + redq[3] + c4[0];
  } else {
    const int j = blockIdx.x - 3200;
    const int tm0 = (j & 7) * 128, tn0 = (j >> 3) * 128;
    f32x4 acc[4][4];
    gemm_core64(qwb, 1024, 1023, tm0, kwb, 1024, 1535, tn0, 1024, As, Bs, acc);
    const int w = t >> 6, l = t & 63;
    const int wr = w >> 1, wc = w & 1;
#pragma unroll
    for (int i = 0; i < 4; i++) {
      const int row0 = tm0 + wr * 64 + i * 16 + (l >> 4) * 4;
#pragma unroll
      for (int jj = 0; jj < 4; jj++) {
        const int col = tn0 + wc * 64 + jj * 16 + (l & 15);
#pragma unroll
        for (int r = 0; r < 4; r++)
          W3[(size_t)(row0 + r) * 1536 + col] = f2bf(acc[i][jj][r]);
      }
    }
  }
}

// ------- kq + vT projections, XCD-swizzled, double-buffered (dyn LDS 64 KB) -------
__global__ __launch_bounds__(256) void gemm_kv_kernel(
    const unsigned short* __restrict__ kn, const unsigned short* __restrict__ vn,
    const unsigned short* __restrict__ W3, const unsigned short* __restrict__ vwt,
    const float* __restrict__ bias3, const float* __restrict__ vb,
    unsigned short* __restrict__ kq, unsigned short* __restrict__ vT) {
  extern __shared__ unsigned short lds[];
  unsigned short* As = lds;            // [2][8192]
  unsigned short* Bs = lds + 16384;    // [2][8192]
  const int id = blockIdx.x;
  const int sw = (id & 7) * 50 + (id >> 3);
  const int z = sw / 200;
  const int rem = sw - z * 200;
  const int tm0 = (rem % 25) * 128, tn0 = (rem / 25) * 128;
  const unsigned short* A = z ? vn : kn;
  const unsigned short* Bt = z ? vwt : W3;
  const float* bias = z ? vb : bias3;
  f32x4 acc[4][4];
  gemm_core_db(A, 1536, 3199, tm0, Bt, 1536, 1023, tn0, 1536, As, Bs, acc);
  const int tid = threadIdx.x;
  const int w = tid >> 6, l = tid & 63;
  const int wr = w >> 1, wc = w & 1;
#pragma unroll
  for (int i = 0; i < 4; i++) {
    const int row0 = tm0 + wr * 64 + i * 16 + (l >> 4) * 4;
#pragma unroll
    for (int j = 0; j < 4; j++) {
      const int col = tn0 + wc * 64 + j * 16 + (l & 15);
      const float bv = bias[col];
#pragma unroll
      for (int r = 0; r < 4; r++) {
        const int row = row0 + r;
        const float val = acc[i][j][r] + bv;
        if (!z) {
          kq[(size_t)row * 1024 + col] = f2bf(val);
        } else {
          const int bb = row / 100;
          const int ll = row - bb * 100;
          vT[((size_t)bb * 1024 + col) * 128 + ll] = f2bf(val);
        }
      }
    }
  }
}

// ---------------- block reduction helper ----------------
__device__ __forceinline__ void block_reduce2(float& s, float& ss, float* red) {
#pragma unroll
  for (int off = 32; off > 0; off >>= 1) {
    s += __shfl_xor(s, off);
    ss += __shfl_xor(ss, off);
  }
  const int wave = threadIdx.x >> 6;
  const int lane = threadIdx.x & 63;
  if (lane == 0) { red[wave * 2] = s; red[wave * 2 + 1] = ss; }
  __syncthreads();
  if (threadIdx.x == 0) {
    float a = 0.f, b = 0.f;
    for (int i = 0; i < 4; i++) { a += red[i * 2]; b += red[i * 2 + 1]; }
    red[0] = a; red[1] = b;
  }
  __syncthreads();
  s = red[0]; ss = red[1];
}

// ---------------- LN vit: [18432][1024] f32 -> bf16 ----------------
__global__ __launch_bounds__(256) void ln_vit_kernel(
    const float* __restrict__ x, const float* __restrict__ w,
    const float* __restrict__ b, unsigned short* __restrict__ out) {
  __shared__ float red[8];
  const int row = blockIdx.x;
  const int t = threadIdx.x;
  const float4 v = ((const float4*)(x + (size_t)row * 1024))[t];
  float s = v.x + v.y + v.z + v.w;
  float ss = v.x * v.x + v.y * v.y + v.z * v.z + v.w * v.w;
  block_reduce2(s, ss, red);
  const float m = s * (1.f / 1024.f);
  const float var = ss * (1.f / 1024.f) - m * m;
  const float rstd = rsqrtf(var + 1e-5f);
  const float4 w4 = ((const float4*)w)[t];
  const float4 b4 = ((const float4*)b)[t];
  ushort4 o;
  o.x = f2bf((v.x - m) * rstd * w4.x + b4.x);
  o.y = f2bf((v.y - m) * rstd * w4.y + b4.y);
  o.z = f2bf((v.z - m) * rstd * w4.z + b4.z);
  o.w = f2bf((v.w - m) * rstd * w4.w + b4.w);
  ((ushort4*)(out + (size_t)row * 1024))[t] = o;
}

// ================= Fused attention v4 (r13-proven) + bijective XCD swizzle =================
// Grid 576 (=8*72), 256 threads. LDS 45824 B -> 3 blocks/CU.
__global__ __launch_bounds__(256) void attfused_kernel(
    const unsigned short* __restrict__ qn, const unsigned short* __restrict__ kq,
    const unsigned short* __restrict__ vT, const float* __restrict__ qbk,
    const int* __restrict__ lengths, const float* __restrict__ vit,
    float* __restrict__ out) {
  __shared__ __align__(16) char smem[45824];
  float* Smat = (float*)smem;
  float* invr = (float*)(smem + 28672);
  float* qb_l = (float*)(smem + 28800);
  const int PB = 20480, BV = 29440;

  const int id = blockIdx.x;
  const int swz = (id & 7) * 72 + (id >> 3);
  const int b = swz / 18;
  const int tm0 = (swz - b * 18) * 32;
  const int t = threadIdx.x;
  const int w = t >> 6, l = t & 63;
  const int lo = l & 15, hi = l >> 4;
  if (t < 128) qb_l[t] = (t < 100) ? qbk[b * 100 + t] : 0.f;

  // ---- phase A: S[32 x 128] = qn_tile @ kq^T ----
  const unsigned short* A = qn + (size_t)b * 576 * 1024;
  const unsigned short* B = kq + (size_t)b * 100 * 1024;
  const int ar = (t & 127) >> 2, ah = t >> 7, ac = (t & 3) << 3;
  const unsigned short* paA = A + (size_t)(tm0 + ar) * 1024 + ah * 32 + ac;
  const unsigned short* pbB[4];
#pragma unroll
  for (int i = 0; i < 4; i++) {
    int rb = (i & 1) * 64 + (t >> 2); if (rb > 99) rb = 99;
    pbB[i] = B + (size_t)rb * 1024 + (i >> 1) * 32 + ((t & 3) << 3);
  }
  const int cw = w << 5;

  f32x4 acc[2][2];
#pragma unroll
  for (int i = 0; i < 2; i++) { acc[i][0] = (f32x4)0.0f; acc[i][1] = (f32x4)0.0f; }

  for (int k0 = 0; k0 < 1024; k0 += 64) {
    gload16(paA + k0, smem + w * 1024);
#pragma unroll
    for (int i = 0; i < 4; i++)
      gload16(pbB[i] + k0, smem + 4096 + i * 4096 + w * 1024);
    __syncthreads();
#pragma unroll
    for (int half = 0; half < 2; half++) {
      short8 a[2], bb[2];
#pragma unroll
      for (int i = 0; i < 2; i++)
        a[i] = *(const short8*)(smem + half * 2048 + (i * 16 + lo) * 64 + hi * 16);
#pragma unroll
      for (int j = 0; j < 2; j++)
        bb[j] = *(const short8*)(smem + 4096 + half * 8192 + (cw + j * 16 + lo) * 64 + hi * 16);
#pragma unroll
      for (int i = 0; i < 2; i++)
#pragma unroll
        for (int j = 0; j < 2; j++)
          acc[i][j] = __builtin_amdgcn_mfma_f32_16x16x32_bf16(a[i], bb[j], acc[i][j], 0, 0, 0);
    }
    __syncthreads();
  }

  // ---- phase B: Smat[c][r] (stride 36) + q-bias; masked softmax (8 lanes/row) ----
#pragma unroll
  for (int i = 0; i < 2; i++) {
    const int r0 = i * 16 + hi * 4;
#pragma unroll
    for (int j = 0; j < 2; j++) {
      const int c = cw + j * 16 + lo;
      const float qb = qb_l[c];
#pragma unroll
      for (int rr = 0; rr < 4; rr++) Smat[c * 36 + r0 + rr] = acc[i][j][rr] + qb;
    }
  }
  __syncthreads();

  const int r = t >> 3, g = t & 7;
  const int len = lengths[b];
  float mx = NEG_FLT_MAX;
#pragma unroll
  for (int i = 0; i < 13; i++) {
    const int ll = g * 13 + i;
    if (ll < 100) {
      const float v = (ll < len) ? Smat[ll * 36 + r] : NEG_FLT_MAX;
      mx = fmaxf(mx, v);
    }
  }
  mx = fmaxf(mx, __shfl_xor(mx, 1));
  mx = fmaxf(mx, __shfl_xor(mx, 2));
  mx = fmaxf(mx, __shfl_xor(mx, 4));
  float sum = 0.f;
#pragma unroll
  for (int i = 0; i < 13; i++) {
    const int ll = g * 13 + i;
    if (ll < 100) {
      const float v = (ll < len) ? Smat[ll * 36 + r] : NEG_FLT_MAX;
      const float e = __expf(v - mx);
      Smat[ll * 36 + r] = e;
      sum += e;
    }
  }
  sum += __shfl_xor(sum, 1);
  sum += __shfl_xor(sum, 2);
  sum += __shfl_xor(sum, 4);
  if (g == 0) invr[r] = 1.f / sum;
  __syncthreads();

  // ---- phase C: P[32][128] bf16, swizzled ----
  {
    const float inv = invr[r];
#pragma unroll
    for (int jj = 0; jj < 4; jj++) {
      const int c0 = g * 16 + jj * 4;
      ushort4 o;
      o.x = (c0 + 0 < 100) ? f2bf(Smat[(c0 + 0) * 36 + r] * inv) : (unsigned short)0;
      o.y = (c0 + 1 < 100) ? f2bf(Smat[(c0 + 1) * 36 + r] * inv) : (unsigned short)0;
      o.z = (c0 + 2 < 100) ? f2bf(Smat[(c0 + 2) * 36 + r] * inv) : (unsigned short)0;
      o.w = (c0 + 3 < 100) ? f2bf(Smat[(c0 + 3) * 36 + r] * inv) : (unsigned short)0;
      const int phys = (r * 256 + g * 32 + jj * 8) ^ ((r & 7) << 4);
      *(ushort4*)(smem + PB + phys) = o;
    }
  }
  __syncthreads();

  // ---- phase D: out = P @ vT^T + vit; 16 N-tiles of 64 cols ----
  const unsigned short* vTb = vT + (size_t)b * 131072;
  const float* vitb = vit + ((size_t)b * 576 + tm0) * 1024;
  float* outb = out + ((size_t)b * 576 + tm0) * 1024;
  const int sBcol = ((t & 15) ^ ((t >> 4) & 7)) << 3;
  for (int nt = 0; nt < 16; ++nt) {
#pragma unroll
    for (int i = 0; i < 4; i++) {
      const int vrow = nt * 64 + i * 16 + (t >> 4);
      gload16(vTb + (size_t)vrow * 128 + sBcol, smem + BV + i * 4096 + w * 1024);
    }
    __syncthreads();
    f32x4 acc2[2];
    acc2[0] = (f32x4)0.0f; acc2[1] = (f32x4)0.0f;
#pragma unroll
    for (int ks = 0; ks < 4; ks++) {
      short8 av[2], bv;
#pragma unroll
      for (int i = 0; i < 2; i++) {
        const int m = i * 16 + lo;
        av[i] = *(const short8*)(smem + PB + ((m * 256 + ks * 64 + hi * 16) ^ ((m & 7) << 4)));
      }
      const int n = (w << 4) + lo;
      bv = *(const short8*)(smem + BV + ((n * 256 + ks * 64 + hi * 16) ^ ((n & 7) << 4)));
      acc2[0] = __builtin_amdgcn_mfma_f32_16x16x32_bf16(av[0], bv, acc2[0], 0, 0, 0);
      acc2[1] = __builtin_amdgcn_mfma_f32_16x16x32_bf16(av[1], bv, acc2[1], 0, 0, 0);
    }
#pragma unroll
    for (int i = 0; i < 2; i++) {
      const int col = (w << 4) + lo;
#pragma unroll
      for (int rr = 0; rr < 4; rr++) {
        const int row = i * 16 + hi * 4 + rr;
        *(float*)(smem + ((row * 256 + col * 4) ^ ((row & 7) << 4))) = acc2[i][rr];
      }
    }
    __syncthreads();
#pragma unroll
    for (int m = 0; m < 2; m++) {
      const int row = m * 16 + (t >> 4);
      const int colb = (t & 15) * 4;
      float4 e = *(const float4*)(smem + ((row * 256 + colb * 4) ^ ((row & 7) << 4)));
      const size_t gidx = (size_t)row * 1024 + nt * 64 + colb;
      float4 vv = *(const float4*)(vitb + gidx);
      e.x += vv.x; e.y += vv.y; e.z += vv.z; e.w += vv.w;
      *(float4*)(outb + gidx) = e;
    }
    __syncthreads();
  }
}

extern "C" void kernel_launch(void* const* d_in, const int* in_sizes, int n_in,
                              void* d_out, int out_size, void* d_ws, size_t ws_size,
                              hipStream_t stream) {
  const float* vit = (const float*)d_in[0];
  const float* box = (const float*)d_in[1];
  const int* lengths = (const int*)d_in[2];
  const float* q_ln_w = (const float*)d_in[3];
  const float* q_ln_b = (const float*)d_in[4];
  const float* q_w = (const float*)d_in[5];
  const float* q_b = (const float*)d_in[6];
  const float* k_ln_w = (const float*)d_in[7];
  const float* k_ln_b = (const float*)d_in[8];
  const float* k_w = (const float*)d_in[9];
  const float* k_b = (const float*)d_in[10];
  const float* v_ln_w = (const float*)d_in[11];
  const float* v_ln_b = (const float*)d_in[12];
  const float* v_w = (const float*)d_in[13];
  const float* v_b = (const float*)d_in[14];
  float* out = (float*)d_out;
  char* ws = (char*)d_ws;

  // Arena [0, 37748736): weight/LN buffers, all dead after gemm_kv -> reused by qn.
  unsigned short* kn    = (unsigned short*)(ws + 0);          // [3200][1536]
  unsigned short* vn    = (unsigned short*)(ws + 9830400);    // [3200][1536]
  unsigned short* v_wt  = (unsigned short*)(ws + 19660800);   // [1024][1536]
  unsigned short* qwb   = (unsigned short*)(ws + 22806528);   // [1024][1024]
  unsigned short* kwb   = (unsigned short*)(ws + 24903680);   // [1536][1024] (scaled)
  unsigned short* W3    = (unsigned short*)(ws + 28049408);   // [1024][1536]
  float*          bias3 = (float*)(ws + 31195136);            // [1024]
  float*          w4    = (float*)(ws + 31199232);            // [1536]
  float*          c4    = (float*)(ws + 31207424);            // [1]
  unsigned short* qn    = (unsigned short*)(ws + 0);          // [18432][1024] (arena reuse)
  // Outside arena (live into attfused):
  float*          qbk   = (float*)(ws + 37748736);            // [3200]
  unsigned short* kq    = (unsigned short*)(ws + 37761536);   // [3200][1024]
  unsigned short* vT    = (unsigned short*)(ws + 44315136);   // [32][1024][128]

  const float scale = 0.03125f;  // 1/sqrt(1024)

  // allow 64 KiB dynamic LDS for the double-buffered kv GEMM
  (void)hipFuncSetAttribute((const void*)gemm_kv_kernel,
                            hipFuncAttributeMaxDynamicSharedMemorySize, 65536);

  // 1. weight prep (wconv + V-transpose + wvec)
  prep_kernel<<<4737, 256, 0, stream>>>(q_w, k_w, v_w, q_b, k_b, scale,
                                        qwb, kwb, v_wt, bias3, w4, c4);

  // 2. ln_box (+fused qbk) + W3 GEMM in one grid
  mid_kernel<<<3296, 256, 0, stream>>>(box, k_ln_w, k_ln_b, v_ln_w, v_ln_b,
                                       qwb, kwb, w4, c4, kn, vn, W3, qbk);

  // 3. kq/vT projections (400 blocks, XCD-swizzled, double-buffered)
  gemm_kv_kernel<<<400, 256, 65536, stream>>>(kn, vn, W3, v_wt, bias3, v_b, kq, vT);

  // 4. LN vit -> qn (arena now dead)
  ln_vit_kernel<<<18432, 256, 0, stream>>>(vit, q_ln_w, q_ln_b, qn);

  // 5. fused attention: scores -> softmax -> @V -> +vit -> out (XCD-swizzled grid)
  attfused_kernel<<<576, 256, 0, stream>>>(
      qn, kq, vT, qbk, lengths, vit, out);

  (void)in_sizes; (void)n_in; (void)out_size; (void)ws_size;
}